// Round 32
// baseline (60.788 us; speedup 1.0000x reference)
//
#include <hip/hip_runtime.h>
#include <cstdint>
#include <cstddef>

#define BATCH 32
#define IMH 512
#define IMW 512
#define KMAX 256

// K1: 256-thr blocks (4 waves) over a 256x16 tile; wave w owns output rows
// 4w..4w+3. Scores computed ONCE into an LDS tile; in-block merge -> 1 list.
#define TILE_ROWS 16
#define NBLKX 2
#define NYB (IMH / TILE_ROWS)          // 32 y-blocks
#define NL1 (NBLKX * NYB)              // 64 lists/image out of K1
#define WCAP 256                       // worst-case strict maxima in 256x4 = 256
#define SSTRIDE 260                    // LDS row stride (floats)

#define TPB2 512                       // tail threads (8 waves)

typedef unsigned long long u64;

__device__ __forceinline__ float sigmoidf_(float x) {
    return 1.0f / (1.0f + expf(-x));
}
__device__ __forceinline__ float scoref_(float r, float u) {
    const float sg = sigmoidf_(r);
    return sg * sg * (1.0f - 0.35f * sigmoidf_(u));
}

// ---------------------------------------------------------------------------
// Register-resident wave bitonic sort/merge (folded compare-exchange,
// R19-verified network).
// ---------------------------------------------------------------------------
#define SHF(v, jj, dm) do {                                         \
    const u64 o_ = __shfl_xor((v), (jj), 64);                       \
    const bool take_ = ((((lane & (jj)) == 0) == (dm)) == ((v) < o_)); \
    (v) = take_ ? o_ : (v);                                         \
} while (0)

#define RMAX(a, b) do {                                             \
    const u64 hi_ = ((a) > (b)) ? (a) : (b);                        \
    const u64 lo_ = ((a) > (b)) ? (b) : (a);                        \
    (a) = hi_; (b) = lo_;                                           \
} while (0)

#define RMIN(a, b) do {                                             \
    const u64 hi_ = ((a) > (b)) ? (a) : (b);                        \
    const u64 lo_ = ((a) > (b)) ? (b) : (a);                        \
    (a) = lo_; (b) = hi_;                                           \
} while (0)

__device__ __forceinline__ void clean256(u64& v0, u64& v1, u64& v2, u64& v3,
                                         const int lane) {
    RMAX(v0, v2); RMAX(v1, v3);
    RMAX(v0, v1); RMAX(v2, v3);
    #pragma unroll
    for (int j = 32; j > 0; j >>= 1) {
        SHF(v0, j, true); SHF(v1, j, true); SHF(v2, j, true); SHF(v3, j, true);
    }
}

__device__ __forceinline__ void sort256(u64& v0, u64& v1, u64& v2, u64& v3,
                                        const int lane) {
    #pragma unroll
    for (int k = 2; k <= 32; k <<= 1) {
        #pragma unroll
        for (int j = k >> 1; j > 0; j >>= 1) {
            const bool dm = ((lane & k) == 0);
            SHF(v0, j, dm); SHF(v1, j, dm); SHF(v2, j, dm); SHF(v3, j, dm);
        }
    }
    #pragma unroll
    for (int j = 32; j > 0; j >>= 1) {
        SHF(v0, j, true); SHF(v1, j, false); SHF(v2, j, true); SHF(v3, j, false);
    }
    RMAX(v0, v1); RMIN(v2, v3);
    #pragma unroll
    for (int j = 32; j > 0; j >>= 1) {
        SHF(v0, j, true); SHF(v1, j, true); SHF(v2, j, false); SHF(v3, j, false);
    }
    clean256(v0, v1, v2, v3, lane);
}

// N=128 over 2 regs (e = r*64 + lane), descending
__device__ __forceinline__ void sort128(u64& v0, u64& v1, const int lane) {
    #pragma unroll
    for (int k = 2; k <= 32; k <<= 1) {
        #pragma unroll
        for (int j = k >> 1; j > 0; j >>= 1) {
            const bool dm = ((lane & k) == 0);
            SHF(v0, j, dm); SHF(v1, j, dm);
        }
    }
    #pragma unroll
    for (int j = 32; j > 0; j >>= 1) {
        SHF(v0, j, true); SHF(v1, j, false);
    }
    RMAX(v0, v1);
    #pragma unroll
    for (int j = 32; j > 0; j >>= 1) {
        SHF(v0, j, true); SHF(v1, j, true);
    }
}

__device__ __forceinline__ void merge256(u64& v0, u64& v1, u64& v2, u64& v3,
                                         u64 w0, u64 w1, u64 w2, u64 w3,
                                         const int lane) {
    const int rl = 63 ^ lane;
    const u64 b0 = __shfl(w3, rl, 64);
    const u64 b1 = __shfl(w2, rl, 64);
    const u64 b2 = __shfl(w1, rl, 64);
    const u64 b3 = __shfl(w0, rl, 64);
    v0 = (v0 > b0) ? v0 : b0;
    v1 = (v1 > b1) ? v1 : b1;
    v2 = (v2 > b2) ? v2 : b2;
    v3 = (v3 > b3) ? v3 : b3;
    clean256(v0, v1, v2, v3, lane);
}

__device__ __forceinline__ void load256(const u64* p, u64& v0, u64& v1,
                                        u64& v2, u64& v3, const int lane) {
    v0 = p[lane]; v1 = p[lane + 64]; v2 = p[lane + 128]; v3 = p[lane + 192];
}
__device__ __forceinline__ void store256(u64* p, u64 v0, u64 v1,
                                         u64 v2, u64 v3, const int lane) {
    p[lane] = v0; p[lane + 64] = v1; p[lane + 128] = v2; p[lane + 192] = v3;
}

// ---------------------------------------------------------------------------
// K1 (R29/R31-verified): 256-thr blocks, 256x16 tile. Phase A: wave-per-row
// FLOAT4 scoring (each score once). Phase B: 3x3 NMS verdict per wave (b128
// quad + shuffle neighbors + eL/eR), ballot append, register sort (sort128
// fast path). Phase C: in-block merge -> the block's sorted top-256.
// key = (score_bits<<32) | ~idx -> unsigned desc == (score desc, idx asc),
// matching lax.top_k's stable tie-break.
// ---------------------------------------------------------------------------
__global__ __launch_bounds__(256, 6)
void score_nms_kernel(const float* __restrict__ route,
                      const float* __restrict__ unc,
                      u64* __restrict__ top) {
    const int b    = blockIdx.z;
    const int t    = threadIdx.x;
    const int w    = t >> 6;
    const int lane = t & 63;
    const int X0   = blockIdx.x * 256;
    const int Y0   = blockIdx.y * TILE_ROWS;

    __shared__ float sT[18][SSTRIDE];    // 18.3 KB
    __shared__ float eL[18], eR[18];
    __shared__ u64 lcand[4 * WCAP];      // 8 KB (append regions, then lists)
    u64* myR = lcand + w * WCAP;

    const float* rB = route + (size_t)b * IMH * IMW;
    const float* uB = unc   + (size_t)b * IMH * IMW;

    // ---- phase A: wave-per-row float4 scoring ----
    #pragma unroll
    for (int k = 0; k < 5; ++k) {
        const int r = 4 * k + w;         // 0..19; rows 18,19 masked
        if (r < 18) {
            const int y = Y0 - 1 + r;
            float4 s4 = make_float4(-INFINITY, -INFINITY, -INFINITY, -INFINITY);
            if (y >= 0 && y < IMH) {
                const size_t o = (size_t)y * IMW + X0 + 4 * lane;
                const float4 r4 = *(const float4*)(rB + o);
                const float4 u4 = *(const float4*)(uB + o);
                s4.x = scoref_(r4.x, u4.x);
                s4.y = scoref_(r4.y, u4.y);
                s4.z = scoref_(r4.z, u4.z);
                s4.w = scoref_(r4.w, u4.w);
            }
            *(float4*)&sT[r][4 * lane] = s4;
        }
    }
    if (t < 36) {
        const int p = t >> 1, side = t & 1;
        const int y = Y0 - 1 + p;
        const int x = side ? (X0 + 256) : (X0 - 1);
        float s = -INFINITY;
        if (y >= 0 && y < IMH && x >= 0 && x < IMW)
            s = scoref_(rB[(size_t)y * IMW + x], uB[(size_t)y * IMW + x]);
        if (side) eR[p] = s; else eL[p] = s;
    }
    __syncthreads();

    // ---- phase B: verdict for output rows Y0+4w .. Y0+4w+3 ----
    const u64 laneMaskLt = (1ull << lane) - 1ull;
    int wcnt = 0;

    float hmP[4], hmC[4], hmN[4], sC[4], sN[4];

    #define LOADROW2(rr, hm, sq) do {                                       \
        const float4 q_ = *(const float4*)&sT[(rr)][4 * lane];              \
        float lft_ = __shfl_up(q_.w, 1, 64);                                \
        if (lane == 0) lft_ = eL[(rr)];                                     \
        float rgt_ = __shfl_down(q_.x, 1, 64);                              \
        if (lane == 63) rgt_ = eR[(rr)];                                    \
        (hm)[0] = fmaxf(fmaxf(lft_, q_.x), q_.y);                           \
        (hm)[1] = fmaxf(fmaxf(q_.x, q_.y), q_.z);                           \
        (hm)[2] = fmaxf(fmaxf(q_.y, q_.z), q_.w);                           \
        (hm)[3] = fmaxf(fmaxf(q_.z, q_.w), rgt_);                           \
        (sq)[0] = q_.x; (sq)[1] = q_.y; (sq)[2] = q_.z; (sq)[3] = q_.w;     \
    } while (0)

    {
        float dump[4];
        LOADROW2(4 * w,     hmP, dump);
        LOADROW2(4 * w + 1, hmC, sC);
    }
    #pragma unroll
    for (int i = 0; i < 4; ++i) {
        LOADROW2(4 * w + 2 + i, hmN, sN);

        const int yo = Y0 + 4 * w + i;
        bool p[4]; int cntT = 0;
        #pragma unroll
        for (int j = 0; j < 4; ++j) {
            const float m9 = fmaxf(fmaxf(hmP[j], hmC[j]), hmN[j]);
            p[j] = (sC[j] >= m9);
            cntT += p[j] ? 1 : 0;
        }
        const u64 B0 = __ballot(cntT & 1);
        const u64 B1 = __ballot(cntT & 2);
        const u64 B2 = __ballot(cntT & 4);
        const int total = __popcll(B0) + 2 * __popcll(B1) + 4 * __popcll(B2);
        if (total > 0) {
            const int prefix = __popcll(B0 & laneMaskLt) + 2 * __popcll(B1 & laneMaskLt)
                             + 4 * __popcll(B2 & laneMaskLt);
            int mb = wcnt + prefix;
            #pragma unroll
            for (int j = 0; j < 4; ++j) {
                if (p[j]) {
                    const unsigned idx = (unsigned)(yo * IMW + (X0 + 4 * lane + j));
                    const u64 key = ((u64)__float_as_uint(sC[j]) << 32) | (unsigned)(~idx);
                    if (mb < WCAP) myR[mb] = key;
                    ++mb;
                }
            }
            wcnt += total;
        }

        #pragma unroll
        for (int j = 0; j < 4; ++j) { hmP[j] = hmC[j]; hmC[j] = hmN[j]; sC[j] = sN[j]; }
    }
    #undef LOADROW2

    // ---- register sort of this wave's candidates (same-wave RAW) ----
    const int m = (wcnt < WCAP) ? wcnt : WCAP;
    u64 a0, a1, a2, a3;
    if (m <= 128) {                      // fast path (~92% of waves)
        a0 = (lane      < m) ? myR[lane]      : 0ull;
        a1 = (lane + 64 < m) ? myR[lane + 64] : 0ull;
        sort128(a0, a1, lane);
        a2 = 0ull; a3 = 0ull;
    } else {
        a0 = (lane       < m) ? myR[lane]       : 0ull;
        a1 = (lane + 64  < m) ? myR[lane + 64]  : 0ull;
        a2 = (lane + 128 < m) ? myR[lane + 128] : 0ull;
        a3 = (lane + 192 < m) ? myR[lane + 192] : 0ull;
        sort256(a0, a1, a2, a3, lane);
    }

    // ---- phase C: in-block merge 4 lists -> 1 (R17-verified pattern) ----
    __syncthreads();                     // append regions no longer needed
    store256(myR, a0, a1, a2, a3, lane); // each wave stores its sorted list
    __syncthreads();

    if ((w & 1) == 0) {                  // w0 merges L0+L1, w2 merges L2+L3
        u64 w0r, w1r, w2r, w3r;
        load256(lcand + (w + 1) * WCAP, w0r, w1r, w2r, w3r, lane);
        merge256(a0, a1, a2, a3, w0r, w1r, w2r, w3r, lane);
        if (w == 2) store256(lcand + 2 * WCAP, a0, a1, a2, a3, lane);
    }
    __syncthreads();

    if (w == 0) {                        // w0 merges (L0+L1) + (L2+L3)
        u64 w0r, w1r, w2r, w3r;
        load256(lcand + 2 * WCAP, w0r, w1r, w2r, w3r, lane);
        merge256(a0, a1, a2, a3, w0r, w1r, w2r, w3r, lane);

        const int list = blockIdx.y * NBLKX + blockIdx.x;
        u64* seg = top + ((size_t)b * NL1 + list) * KMAX;
        store256(seg, a0, a1, a2, a3, lane);
    }
}

// ---------------------------------------------------------------------------
// K2 (tail, takes all 64 lists): 1 block/image x 512 threads.
// Round 0: pairwise top-256 selection straight FROM GLOBAL (64 -> 32 lists
// into 64KB LDS) + 8-phase bitonic clean. Then 5 standard LDS rounds
// (32 -> 1). Final list = exact sorted global top-256 -> ROI epilogue.
// ---------------------------------------------------------------------------
__global__ __launch_bounds__(TPB2)
void tail_kernel(const u64* __restrict__ top,
                 const float* __restrict__ scale,
                 const float* __restrict__ unc,
                 const int* __restrict__ imh,
                 const int* __restrict__ imw,
                 float* __restrict__ rois,
                 float* __restrict__ scoresOut,
                 float* __restrict__ validOut) {
    const int b   = blockIdx.x;
    const int tid = threadIdx.x;

    __shared__ u64 bufA[32 * KMAX];          // 64 KB
    __shared__ u64 bufB[16 * KMAX];          // 32 KB

    const u64* tb = top + (size_t)b * NL1 * KMAX;

    // ---- round 0: 64 -> 32, selection from global ----
    for (int p = tid; p < 32 * KMAX; p += TPB2) {
        const int h = p >> 8;                // output list 0..31
        const int i = p & (KMAX - 1);
        const u64 a = tb[(size_t)(2 * h) * KMAX + i];
        const u64 c = tb[(size_t)(2 * h + 1) * KMAX + (KMAX - 1 - i)];
        bufA[p] = (a > c) ? a : c;
    }
    __syncthreads();
    for (int j = KMAX >> 1; j > 0; j >>= 1) {       // clean all 32 groups
        for (int p = tid; p < 16 * KMAX; p += TPB2) {
            const int i   = ((p & ~(j - 1)) << 1) | (p & (j - 1));
            const int ixj = i | j;
            const u64 a = bufA[i];
            const u64 c = bufA[ixj];
            if (a < c) { bufA[i] = c; bufA[ixj] = a; }
        }
        __syncthreads();
    }

    // ---- rounds 1..5: standard LDS pairwise tree (32 -> 1) ----
    u64* src = bufA;
    u64* dst = bufB;
    int nl = 32;
    while (nl > 1) {
        const int half = nl >> 1;
        const int E = half * KMAX;
        for (int p = tid; p < E; p += TPB2) {
            const int h = p >> 8;
            const int i = p & (KMAX - 1);
            const u64 a = src[(2 * h) * KMAX + i];
            const u64 c = src[(2 * h + 1) * KMAX + (KMAX - 1 - i)];
            dst[p] = (a > c) ? a : c;
        }
        __syncthreads();
        for (int j = KMAX >> 1; j > 0; j >>= 1) {
            for (int p = tid; p < (E >> 1); p += TPB2) {
                const int i   = ((p & ~(j - 1)) << 1) | (p & (j - 1));
                const int ixj = i | j;
                const u64 a = dst[i];
                const u64 c = dst[ixj];
                if (a < c) { dst[i] = c; dst[ixj] = a; }
            }
            __syncthreads();
        }
        u64* t = src; src = dst; dst = t;
        nl = half;
    }

    // ---- epilogue: src[0..255] = exact sorted top-256 ----
    if (tid < KMAX) {
        const u64 k = src[tid];
        const float value = __uint_as_float((unsigned)(k >> 32));
        const bool valid  = (k != 0ull) && (value > 0.0f);

        float r0 = 0.f, r1 = 0.f, r2 = 0.f, r3 = 0.f, r4 = 0.f, sv = 0.f, vv = 0.f;
        if (valid) {
            const unsigned idx = ~(unsigned)(k & 0xFFFFFFFFull);
            const int y = (int)(idx / IMW);
            const int x = (int)(idx % IMW);
            const float cx = ((float)x + 0.5f) * 4.0f;
            const float cy = ((float)y + 0.5f) * 4.0f;
            const float sg = scale[(size_t)b * IMH * IMW + idx];
            const float uu = unc[(size_t)b * IMH * IMW + idx];
            const float su = sigmoidf_(uu);
            float side = 32.0f + sigmoidf_(sg) * (512.0f - 32.0f);
            side = side * (1.0f + 0.25f * su);
            const float half2 = side * 0.5f;
            const float fw = (float)imw[0];
            const float fh = (float)imh[0];
            r0 = (float)b;
            r1 = fminf(fmaxf(cx - half2, 0.0f), fw - 1.0f);
            r2 = fminf(fmaxf(cy - half2, 0.0f), fh - 1.0f);
            r3 = fminf(fmaxf(cx + half2, 1.0f), fw);
            r4 = fminf(fmaxf(cy + half2, 1.0f), fh);
            sv = value;
            vv = 1.0f;
        }
        float* roiP = rois + ((size_t)b * KMAX + tid) * 5;
        roiP[0] = r0; roiP[1] = r1; roiP[2] = r2; roiP[3] = r3; roiP[4] = r4;
        scoresOut[b * KMAX + tid] = sv;
        validOut[b * KMAX + tid]  = vv;
    }
}

extern "C" void kernel_launch(void* const* d_in, const int* in_sizes, int n_in,
                              void* d_out, int out_size, void* d_ws, size_t ws_size,
                              hipStream_t stream) {
    const float* route = (const float*)d_in[0];
    const float* scale = (const float*)d_in[1];
    const float* unc   = (const float*)d_in[2];
    const int*   imh   = (const int*)d_in[3];
    const int*   imw   = (const int*)d_in[4];

    // ws layout: [top 64 lists = 4MB]
    u64* top = (u64*)d_ws;

    float* rois      = (float*)d_out;                       // [B, 256, 5]
    float* scoresOut = rois + (size_t)BATCH * KMAX * 5;     // [B, 256]
    float* validOut  = scoresOut + (size_t)BATCH * KMAX;    // [B, 256]

    dim3 grid1(NBLKX, NYB, BATCH);         // 2 x 32 x 32 blocks, 4 waves each
    score_nms_kernel<<<grid1, 256, 0, stream>>>(route, unc, top);

    tail_kernel<<<BATCH, TPB2, 0, stream>>>(top, scale, unc,
                                            imh, imw, rois, scoresOut, validOut);
}

// Round 33
// 51.924 us; speedup vs baseline: 1.1707x; 1.1707x over previous
//
#include <hip/hip_runtime.h>
#include <cstdint>
#include <cstddef>

#define BATCH 32
#define IMH 512
#define IMW 512
#define KMAX 256

// K1: 256-thr blocks (4 waves) over a 256x16 tile; wave w owns output rows
// 4w..4w+3. Scores computed ONCE into an LDS tile; in-block merge -> 1 list.
#define TILE_ROWS 16
#define NBLKX 2
#define NYB (IMH / TILE_ROWS)          // 32 y-blocks
#define NL1 (NBLKX * NYB)              // 64 lists/image out of K1
#define NMID (NL1 / 4)                 // 16 after merge4
#define WCAP 256                       // worst-case strict maxima in 256x4 = 256
#define SSTRIDE 260                    // LDS row stride (floats)

#define TPB2 512                       // tail threads (8 waves)

typedef unsigned long long u64;

__device__ __forceinline__ float sigmoidf_(float x) {
    return 1.0f / (1.0f + expf(-x));
}
__device__ __forceinline__ float scoref_(float r, float u) {
    const float sg = sigmoidf_(r);
    return sg * sg * (1.0f - 0.35f * sigmoidf_(u));
}

// ---------------------------------------------------------------------------
// Register-resident wave bitonic sort/merge (folded compare-exchange,
// R19-verified network).
// ---------------------------------------------------------------------------
#define SHF(v, jj, dm) do {                                         \
    const u64 o_ = __shfl_xor((v), (jj), 64);                       \
    const bool take_ = ((((lane & (jj)) == 0) == (dm)) == ((v) < o_)); \
    (v) = take_ ? o_ : (v);                                         \
} while (0)

#define RMAX(a, b) do {                                             \
    const u64 hi_ = ((a) > (b)) ? (a) : (b);                        \
    const u64 lo_ = ((a) > (b)) ? (b) : (a);                        \
    (a) = hi_; (b) = lo_;                                           \
} while (0)

#define RMIN(a, b) do {                                             \
    const u64 hi_ = ((a) > (b)) ? (a) : (b);                        \
    const u64 lo_ = ((a) > (b)) ? (b) : (a);                        \
    (a) = lo_; (b) = hi_;                                           \
} while (0)

__device__ __forceinline__ void clean256(u64& v0, u64& v1, u64& v2, u64& v3,
                                         const int lane) {
    RMAX(v0, v2); RMAX(v1, v3);
    RMAX(v0, v1); RMAX(v2, v3);
    #pragma unroll
    for (int j = 32; j > 0; j >>= 1) {
        SHF(v0, j, true); SHF(v1, j, true); SHF(v2, j, true); SHF(v3, j, true);
    }
}

__device__ __forceinline__ void sort256(u64& v0, u64& v1, u64& v2, u64& v3,
                                        const int lane) {
    #pragma unroll
    for (int k = 2; k <= 32; k <<= 1) {
        #pragma unroll
        for (int j = k >> 1; j > 0; j >>= 1) {
            const bool dm = ((lane & k) == 0);
            SHF(v0, j, dm); SHF(v1, j, dm); SHF(v2, j, dm); SHF(v3, j, dm);
        }
    }
    #pragma unroll
    for (int j = 32; j > 0; j >>= 1) {
        SHF(v0, j, true); SHF(v1, j, false); SHF(v2, j, true); SHF(v3, j, false);
    }
    RMAX(v0, v1); RMIN(v2, v3);
    #pragma unroll
    for (int j = 32; j > 0; j >>= 1) {
        SHF(v0, j, true); SHF(v1, j, true); SHF(v2, j, false); SHF(v3, j, false);
    }
    clean256(v0, v1, v2, v3, lane);
}

// N=128 over 2 regs (e = r*64 + lane), descending
__device__ __forceinline__ void sort128(u64& v0, u64& v1, const int lane) {
    #pragma unroll
    for (int k = 2; k <= 32; k <<= 1) {
        #pragma unroll
        for (int j = k >> 1; j > 0; j >>= 1) {
            const bool dm = ((lane & k) == 0);
            SHF(v0, j, dm); SHF(v1, j, dm);
        }
    }
    #pragma unroll
    for (int j = 32; j > 0; j >>= 1) {
        SHF(v0, j, true); SHF(v1, j, false);
    }
    RMAX(v0, v1);
    #pragma unroll
    for (int j = 32; j > 0; j >>= 1) {
        SHF(v0, j, true); SHF(v1, j, true);
    }
}

__device__ __forceinline__ void merge256(u64& v0, u64& v1, u64& v2, u64& v3,
                                         u64 w0, u64 w1, u64 w2, u64 w3,
                                         const int lane) {
    const int rl = 63 ^ lane;
    const u64 b0 = __shfl(w3, rl, 64);
    const u64 b1 = __shfl(w2, rl, 64);
    const u64 b2 = __shfl(w1, rl, 64);
    const u64 b3 = __shfl(w0, rl, 64);
    v0 = (v0 > b0) ? v0 : b0;
    v1 = (v1 > b1) ? v1 : b1;
    v2 = (v2 > b2) ? v2 : b2;
    v3 = (v3 > b3) ? v3 : b3;
    clean256(v0, v1, v2, v3, lane);
}

__device__ __forceinline__ void load256(const u64* p, u64& v0, u64& v1,
                                        u64& v2, u64& v3, const int lane) {
    v0 = p[lane]; v1 = p[lane + 64]; v2 = p[lane + 128]; v3 = p[lane + 192];
}
__device__ __forceinline__ void store256(u64* p, u64 v0, u64 v1,
                                         u64 v2, u64 v3, const int lane) {
    p[lane] = v0; p[lane + 64] = v1; p[lane + 128] = v2; p[lane + 192] = v3;
}

__device__ __forceinline__ void merge4s(const u64* p,
                                        u64& a0, u64& a1, u64& a2, u64& a3,
                                        const int lane) {
    load256(p, a0, a1, a2, a3, lane);
    u64 w0, w1, w2, w3;
    load256(p + KMAX, w0, w1, w2, w3, lane);
    merge256(a0, a1, a2, a3, w0, w1, w2, w3, lane);
    u64 c0, c1, c2, c3;
    load256(p + 2 * KMAX, c0, c1, c2, c3, lane);
    load256(p + 3 * KMAX, w0, w1, w2, w3, lane);
    merge256(c0, c1, c2, c3, w0, w1, w2, w3, lane);
    merge256(a0, a1, a2, a3, c0, c1, c2, c3, lane);
}

// ---------------------------------------------------------------------------
// K1 (R29/R31-verified): 256-thr blocks, 256x16 tile.
// Phase A: wave-per-row FLOAT4 scoring (each score once; 16B/lane coalesced
// loads; conflict-free float4 LDS stores). Phase B: 3x3 NMS verdict per wave
// (b128 quad + shuffle neighbors + eL/eR), ballot append, register sort
// (sort128 fast path). Phase C: in-block merge (R17-verified pattern) -> the
// block's sorted top-256 = ONE list per block.
// key = (score_bits<<32) | ~idx -> unsigned desc == (score desc, idx asc),
// matching lax.top_k's stable tie-break.
// ---------------------------------------------------------------------------
__global__ __launch_bounds__(256, 6)
void score_nms_kernel(const float* __restrict__ route,
                      const float* __restrict__ unc,
                      u64* __restrict__ top) {
    const int b    = blockIdx.z;
    const int t    = threadIdx.x;
    const int w    = t >> 6;
    const int lane = t & 63;
    const int X0   = blockIdx.x * 256;
    const int Y0   = blockIdx.y * TILE_ROWS;

    __shared__ float sT[18][SSTRIDE];    // 18.3 KB
    __shared__ float eL[18], eR[18];
    __shared__ u64 lcand[4 * WCAP];      // 8 KB (append regions, then lists)
    u64* myR = lcand + w * WCAP;

    const float* rB = route + (size_t)b * IMH * IMW;
    const float* uB = unc   + (size_t)b * IMH * IMW;

    // ---- phase A: wave-per-row float4 scoring ----
    #pragma unroll
    for (int k = 0; k < 5; ++k) {
        const int r = 4 * k + w;         // 0..19; rows 18,19 masked
        if (r < 18) {
            const int y = Y0 - 1 + r;
            float4 s4 = make_float4(-INFINITY, -INFINITY, -INFINITY, -INFINITY);
            if (y >= 0 && y < IMH) {
                const size_t o = (size_t)y * IMW + X0 + 4 * lane;
                const float4 r4 = *(const float4*)(rB + o);
                const float4 u4 = *(const float4*)(uB + o);
                s4.x = scoref_(r4.x, u4.x);
                s4.y = scoref_(r4.y, u4.y);
                s4.z = scoref_(r4.z, u4.z);
                s4.w = scoref_(r4.w, u4.w);
            }
            *(float4*)&sT[r][4 * lane] = s4;
        }
    }
    if (t < 36) {
        const int p = t >> 1, side = t & 1;
        const int y = Y0 - 1 + p;
        const int x = side ? (X0 + 256) : (X0 - 1);
        float s = -INFINITY;
        if (y >= 0 && y < IMH && x >= 0 && x < IMW)
            s = scoref_(rB[(size_t)y * IMW + x], uB[(size_t)y * IMW + x]);
        if (side) eR[p] = s; else eL[p] = s;
    }
    __syncthreads();

    // ---- phase B: verdict for output rows Y0+4w .. Y0+4w+3 ----
    const u64 laneMaskLt = (1ull << lane) - 1ull;
    int wcnt = 0;

    float hmP[4], hmC[4], hmN[4], sC[4], sN[4];

    #define LOADROW2(rr, hm, sq) do {                                       \
        const float4 q_ = *(const float4*)&sT[(rr)][4 * lane];              \
        float lft_ = __shfl_up(q_.w, 1, 64);                                \
        if (lane == 0) lft_ = eL[(rr)];                                     \
        float rgt_ = __shfl_down(q_.x, 1, 64);                              \
        if (lane == 63) rgt_ = eR[(rr)];                                    \
        (hm)[0] = fmaxf(fmaxf(lft_, q_.x), q_.y);                           \
        (hm)[1] = fmaxf(fmaxf(q_.x, q_.y), q_.z);                           \
        (hm)[2] = fmaxf(fmaxf(q_.y, q_.z), q_.w);                           \
        (hm)[3] = fmaxf(fmaxf(q_.z, q_.w), rgt_);                           \
        (sq)[0] = q_.x; (sq)[1] = q_.y; (sq)[2] = q_.z; (sq)[3] = q_.w;     \
    } while (0)

    {
        float dump[4];
        LOADROW2(4 * w,     hmP, dump);
        LOADROW2(4 * w + 1, hmC, sC);
    }
    #pragma unroll
    for (int i = 0; i < 4; ++i) {
        LOADROW2(4 * w + 2 + i, hmN, sN);

        const int yo = Y0 + 4 * w + i;
        bool p[4]; int cntT = 0;
        #pragma unroll
        for (int j = 0; j < 4; ++j) {
            const float m9 = fmaxf(fmaxf(hmP[j], hmC[j]), hmN[j]);
            p[j] = (sC[j] >= m9);
            cntT += p[j] ? 1 : 0;
        }
        const u64 B0 = __ballot(cntT & 1);
        const u64 B1 = __ballot(cntT & 2);
        const u64 B2 = __ballot(cntT & 4);
        const int total = __popcll(B0) + 2 * __popcll(B1) + 4 * __popcll(B2);
        if (total > 0) {
            const int prefix = __popcll(B0 & laneMaskLt) + 2 * __popcll(B1 & laneMaskLt)
                             + 4 * __popcll(B2 & laneMaskLt);
            int mb = wcnt + prefix;
            #pragma unroll
            for (int j = 0; j < 4; ++j) {
                if (p[j]) {
                    const unsigned idx = (unsigned)(yo * IMW + (X0 + 4 * lane + j));
                    const u64 key = ((u64)__float_as_uint(sC[j]) << 32) | (unsigned)(~idx);
                    if (mb < WCAP) myR[mb] = key;
                    ++mb;
                }
            }
            wcnt += total;
        }

        #pragma unroll
        for (int j = 0; j < 4; ++j) { hmP[j] = hmC[j]; hmC[j] = hmN[j]; sC[j] = sN[j]; }
    }
    #undef LOADROW2

    // ---- register sort of this wave's candidates (same-wave RAW) ----
    const int m = (wcnt < WCAP) ? wcnt : WCAP;
    u64 a0, a1, a2, a3;
    if (m <= 128) {                      // fast path (~92% of waves)
        a0 = (lane      < m) ? myR[lane]      : 0ull;
        a1 = (lane + 64 < m) ? myR[lane + 64] : 0ull;
        sort128(a0, a1, lane);
        a2 = 0ull; a3 = 0ull;
    } else {
        a0 = (lane       < m) ? myR[lane]       : 0ull;
        a1 = (lane + 64  < m) ? myR[lane + 64]  : 0ull;
        a2 = (lane + 128 < m) ? myR[lane + 128] : 0ull;
        a3 = (lane + 192 < m) ? myR[lane + 192] : 0ull;
        sort256(a0, a1, a2, a3, lane);
    }

    // ---- phase C: in-block merge 4 lists -> 1 (R17-verified pattern) ----
    __syncthreads();                     // append regions no longer needed
    store256(myR, a0, a1, a2, a3, lane); // each wave stores its sorted list
    __syncthreads();

    if ((w & 1) == 0) {                  // w0 merges L0+L1, w2 merges L2+L3
        u64 w0r, w1r, w2r, w3r;
        load256(lcand + (w + 1) * WCAP, w0r, w1r, w2r, w3r, lane);
        merge256(a0, a1, a2, a3, w0r, w1r, w2r, w3r, lane);
        if (w == 2) store256(lcand + 2 * WCAP, a0, a1, a2, a3, lane);
    }
    __syncthreads();

    if (w == 0) {                        // w0 merges (L0+L1) + (L2+L3)
        u64 w0r, w1r, w2r, w3r;
        load256(lcand + 2 * WCAP, w0r, w1r, w2r, w3r, lane);
        merge256(a0, a1, a2, a3, w0r, w1r, w2r, w3r, lane);

        const int list = blockIdx.y * NBLKX + blockIdx.x;
        u64* seg = top + ((size_t)b * NL1 + list) * KMAX;
        store256(seg, a0, a1, a2, a3, lane);
    }
}

// ---------------------------------------------------------------------------
// K2 (R22-verified): 128-thr blocks = 2 independent waves; each wave
// register-merges 4 sorted lists -> 1. 64 -> 16.
// ---------------------------------------------------------------------------
__global__ __launch_bounds__(128)
void merge4_kernel(const u64* __restrict__ in, int nin,
                   u64* __restrict__ out_) {
    const int w    = threadIdx.x >> 6;
    const int lane = threadIdx.x & 63;
    const int o    = blockIdx.x * 2 + w;
    const int b    = blockIdx.y;
    const int nout = nin / 4;
    if (o >= nout) return;

    const u64* L = in + ((size_t)b * nin + o * 4) * KMAX;
    u64 a0, a1, a2, a3;
    merge4s(L, a0, a1, a2, a3, lane);

    u64* out = out_ + ((size_t)b * nout + o) * KMAX;
    store256(out, a0, a1, a2, a3, lane);
}

// ---------------------------------------------------------------------------
// K3 (R21-verified tail): 1 block/image x 512 threads. 16 sorted-desc
// 256-lists -> 4 rounds of pairwise top-256 merge (D[i] = max(A[i], B[255-i])
// + 8-phase bitonic clean). Final list = exact sorted top-256 -> ROI epilogue.
// ---------------------------------------------------------------------------
__global__ __launch_bounds__(TPB2)
void tail_kernel(const u64* __restrict__ mid,
                 const float* __restrict__ scale,
                 const float* __restrict__ unc,
                 const int* __restrict__ imh,
                 const int* __restrict__ imw,
                 float* __restrict__ rois,
                 float* __restrict__ scoresOut,
                 float* __restrict__ validOut) {
    const int b   = blockIdx.x;
    const int tid = threadIdx.x;

    __shared__ u64 bufA[NMID * KMAX];        // 32 KB
    __shared__ u64 bufB[(NMID / 2) * KMAX];  // 16 KB

    const u64* tb = mid + (size_t)b * NMID * KMAX;
    for (int i = tid; i < NMID * KMAX; i += TPB2) bufA[i] = tb[i];
    __syncthreads();

    u64* src = bufA;
    u64* dst = bufB;
    int nl = NMID;
    while (nl > 1) {
        const int half = nl >> 1;
        const int E = half * KMAX;
        for (int p = tid; p < E; p += TPB2) {
            const int h = p >> 8;
            const int i = p & (KMAX - 1);
            const u64 a = src[(2 * h) * KMAX + i];
            const u64 c = src[(2 * h + 1) * KMAX + (KMAX - 1 - i)];
            dst[p] = (a > c) ? a : c;
        }
        __syncthreads();
        for (int j = KMAX >> 1; j > 0; j >>= 1) {
            for (int p = tid; p < (E >> 1); p += TPB2) {
                const int i   = ((p & ~(j - 1)) << 1) | (p & (j - 1));
                const int ixj = i | j;
                const u64 a = dst[i];
                const u64 c = dst[ixj];
                if (a < c) { dst[i] = c; dst[ixj] = a; }
            }
            __syncthreads();
        }
        u64* t = src; src = dst; dst = t;
        nl = half;
    }

    if (tid < KMAX) {
        const u64 k = src[tid];
        const float value = __uint_as_float((unsigned)(k >> 32));
        const bool valid  = (k != 0ull) && (value > 0.0f);

        float r0 = 0.f, r1 = 0.f, r2 = 0.f, r3 = 0.f, r4 = 0.f, sv = 0.f, vv = 0.f;
        if (valid) {
            const unsigned idx = ~(unsigned)(k & 0xFFFFFFFFull);
            const int y = (int)(idx / IMW);
            const int x = (int)(idx % IMW);
            const float cx = ((float)x + 0.5f) * 4.0f;
            const float cy = ((float)y + 0.5f) * 4.0f;
            const float sg = scale[(size_t)b * IMH * IMW + idx];
            const float uu = unc[(size_t)b * IMH * IMW + idx];
            const float su = sigmoidf_(uu);
            float side = 32.0f + sigmoidf_(sg) * (512.0f - 32.0f);
            side = side * (1.0f + 0.25f * su);
            const float half2 = side * 0.5f;
            const float fw = (float)imw[0];
            const float fh = (float)imh[0];
            r0 = (float)b;
            r1 = fminf(fmaxf(cx - half2, 0.0f), fw - 1.0f);
            r2 = fminf(fmaxf(cy - half2, 0.0f), fh - 1.0f);
            r3 = fminf(fmaxf(cx + half2, 1.0f), fw);
            r4 = fminf(fmaxf(cy + half2, 1.0f), fh);
            sv = value;
            vv = 1.0f;
        }
        float* roiP = rois + ((size_t)b * KMAX + tid) * 5;
        roiP[0] = r0; roiP[1] = r1; roiP[2] = r2; roiP[3] = r3; roiP[4] = r4;
        scoresOut[b * KMAX + tid] = sv;
        validOut[b * KMAX + tid]  = vv;
    }
}

extern "C" void kernel_launch(void* const* d_in, const int* in_sizes, int n_in,
                              void* d_out, int out_size, void* d_ws, size_t ws_size,
                              hipStream_t stream) {
    const float* route = (const float*)d_in[0];
    const float* scale = (const float*)d_in[1];
    const float* unc   = (const float*)d_in[2];
    const int*   imh   = (const int*)d_in[3];
    const int*   imw   = (const int*)d_in[4];

    // ws layout: [top 64 lists = 4MB][mid 16 lists = 1MB]
    u64* top = (u64*)d_ws;
    u64* mid = top + (size_t)BATCH * NL1 * KMAX;

    float* rois      = (float*)d_out;                       // [B, 256, 5]
    float* scoresOut = rois + (size_t)BATCH * KMAX * 5;     // [B, 256]
    float* validOut  = scoresOut + (size_t)BATCH * KMAX;    // [B, 256]

    dim3 grid1(NBLKX, NYB, BATCH);         // 2 x 32 x 32 blocks, 4 waves each
    score_nms_kernel<<<grid1, 256, 0, stream>>>(route, unc, top);

    dim3 grid2(NMID / 2, BATCH);           // 8 x 32 blocks, 2 waves each
    merge4_kernel<<<grid2, 128, 0, stream>>>(top, NL1, mid);

    tail_kernel<<<BATCH, TPB2, 0, stream>>>(mid, scale, unc,
                                            imh, imw, rois, scoresOut, validOut);
}